// Round 9
// baseline (139.428 us; speedup 1.0000x reference)
//
#include <hip/hip_runtime.h>

#define LLEN 65536
#define CIN 64
#define COUT 64
#define LTILE 1024   // l positions per tile (256 threads x 4)
#define TPB 2        // tiles per block (software pipeline depth)

typedef float f32x4 __attribute__((ext_vector_type(4)));
typedef unsigned long long u64;

// Per-co constant record, 64 B so the co-loop fetch is one s_load_dwordx16.
struct __align__(64) WRec {
    u64 p0, p1, p2;                 // sign words (bit=1 iff w>0) for k=0,1,2
    float A;    // wscale * sum_nnz + bias
    float S;    // -2 * wscale
    float Bv, G, Z;                 // RPReLU beta, gamma, zeta
    float f0, f2;                   // 0.5*nnz(k=0), 0.5*nnz(k=2) edge fixups
    float pad[3];
};

__global__ void pack_weights(const float* __restrict__ w,
                             const float* __restrict__ wscale,
                             const float* __restrict__ bias,
                             const float* __restrict__ beta,
                             const float* __restrict__ gamma,
                             const float* __restrict__ zeta,
                             WRec* __restrict__ rec) {
    int co = threadIdx.x;
    if (co >= COUT) return;
    u64 p[3];
    int nnz[3], ntot = 0;
    for (int k = 0; k < 3; ++k) {
        u64 pos = 0ull, nz = 0ull;
        for (int ci = 0; ci < CIN; ++ci) {
            float wv = w[co * (CIN * 3) + ci * 3 + k];
            pos |= ((u64)(wv > 0.0f)) << ci;
            nz  |= ((u64)(wv != 0.0f)) << ci;
        }
        p[k] = pos;
        nnz[k] = __popcll(nz);
        ntot += nnz[k];
    }
    WRec r;
    float s = wscale[co];
    r.p0 = p[0]; r.p1 = p[1]; r.p2 = p[2];
    r.A  = s * (float)ntot + bias[co];
    r.S  = -2.0f * s;
    r.Bv = beta[co]; r.G = gamma[co]; r.Z = zeta[co];
    r.f0 = 0.5f * (float)nnz[0];
    r.f2 = 0.5f * (float)nnz[2];
    r.pad[0] = r.pad[1] = r.pad[2] = 0.0f;
    rec[co] = r;
}

__device__ __forceinline__ float rprelu(float y, float B, float G, float Z) {
    float xs = y - G;
    return (y > G) ? (xs + Z) : fmaf(B, xs, Z);
}

// EDGE: 0 = interior, 1 = tile contains l==0, 2 = tile contains l==LLEN-1.
template <int EDGE>
__device__ __forceinline__ void co_range(const WRec* __restrict__ rec,
                                         int co0, int co1,
                                         u64 xq0, u64 xq1, u64 xq2,
                                         u64 xq3, u64 xq4, u64 xq5,
                                         bool fixlane, float* __restrict__ outp) {
    #pragma unroll 4
    for (int co = co0; co < co1; ++co) {
        const WRec r = rec[co];   // uniform address -> scalar loads
        float fx = (float)(__popcll(xq0 ^ r.p0) + __popcll(xq1 ^ r.p1)
                         + __popcll(xq2 ^ r.p2));
        float fy = (float)(__popcll(xq1 ^ r.p0) + __popcll(xq2 ^ r.p1)
                         + __popcll(xq3 ^ r.p2));
        float fz = (float)(__popcll(xq2 ^ r.p0) + __popcll(xq3 ^ r.p1)
                         + __popcll(xq4 ^ r.p2));
        float fw = (float)(__popcll(xq3 ^ r.p0) + __popcll(xq4 ^ r.p1)
                         + __popcll(xq5 ^ r.p2));
        if (EDGE == 1 && fixlane)   // l==0 (o.x): k=0 term is zero padding
            fx = (float)(__popcll(xq1 ^ r.p1) + __popcll(xq2 ^ r.p2)) + r.f0;
        if (EDGE == 2 && fixlane)   // l==LLEN-1 (o.w): k=2 term is zero padding
            fw = (float)(__popcll(xq3 ^ r.p0) + __popcll(xq4 ^ r.p1)) + r.f2;
        f32x4 o;
        o.x = rprelu(fmaf(r.S, fx, r.A), r.Bv, r.G, r.Z);
        o.y = rprelu(fmaf(r.S, fy, r.A), r.Bv, r.G, r.Z);
        o.z = rprelu(fmaf(r.S, fz, r.A), r.Bv, r.G, r.Z);
        o.w = rprelu(fmaf(r.S, fw, r.A), r.Bv, r.G, r.Z);
        __builtin_nontemporal_store(o, (f32x4*)(outp + (size_t)co * LLEN));
    }
}

// Iteration 0 body: compute tile0 (quarters of 16 co) while prefetching and
// packing tile1 in 4 interleaved 16-row batches (one batch in flight at a
// time: 64 VGPR payload; each ~16-co quarter hides one HBM batch latency).
template <int EDGE0>
__device__ __forceinline__ void iter0(const WRec* __restrict__ rec,
                                      const float* __restrict__ xb1,
                                      const float* __restrict__ alpha,
                                      u64 a0, u64 a1, u64 a2, u64 a3, u64 a4, u64 a5,
                                      bool fix0, float* __restrict__ outp0,
                                      u64& n0, u64& n1, u64& n2, u64& n3) {
    #pragma unroll
    for (int q = 0; q < 4; ++q) {
        f32x4 buf[16];
        #pragma unroll
        for (int jj = 0; jj < 16; ++jj)
            buf[jj] = *(const f32x4*)(xb1 + (size_t)(q * 16 + jj) * LLEN);
        co_range<EDGE0>(rec, q * 16, q * 16 + 16, a0, a1, a2, a3, a4, a5,
                        fix0, outp0);
        #pragma unroll
        for (int jj = 0; jj < 16; ++jj) {
            const int ci = q * 16 + jj;
            const float a = alpha[ci];             // uniform -> s_load
            n0 |= ((u64)(buf[jj].x >= a)) << ci;
            n1 |= ((u64)(buf[jj].y >= a)) << ci;
            n2 |= ((u64)(buf[jj].z >= a)) << ci;
            n3 |= ((u64)(buf[jj].w >= a)) << ci;
        }
    }
}

// ---------------------------------------------------------------------------
// Pipelined main kernel: block = (batch b, 2 consecutive 1024-l tiles).
// Prologue packs tile0 (R6 structure). Then compute(tile0) runs with the
// tile1 loads interleaved in flight; one barrier per tile protects the LDS
// word exchange. Tile1's low halo is xw[0][LTILE] (free, no gather).
// ---------------------------------------------------------------------------
__global__ void __launch_bounds__(256, 2) bconv_kernel(
        const float* __restrict__ x,
        const float* __restrict__ alpha,
        const WRec* __restrict__ rec,
        float* __restrict__ out) {
    __shared__ u64 xw[2][LTILE + 2];   // xw[p][i] = word for l = lbase_p + i - 1

    const int t = threadIdx.x;
    const int b = blockIdx.y;
    const int lbase0 = blockIdx.x * (LTILE * TPB);
    const int lbase1 = lbase0 + LTILE;
    const float* xrow = x + (size_t)b * CIN * LLEN;

    // ---- prologue: load + pack tile0 ----
    {
        const float* xb = xrow + lbase0 + 4 * t;
        u64 w0 = 0, w1 = 0, w2 = 0, w3 = 0;
        #pragma unroll 16
        for (int ci = 0; ci < CIN; ++ci) {
            const f32x4 v = *(const f32x4*)(xb + (size_t)ci * LLEN);
            const float a = alpha[ci];             // uniform -> s_load
            w0 |= ((u64)(v.x >= a)) << ci;
            w1 |= ((u64)(v.y >= a)) << ci;
            w2 |= ((u64)(v.z >= a)) << ci;
            w3 |= ((u64)(v.w >= a)) << ci;
        }
        xw[0][4 * t + 1] = w0;
        xw[0][4 * t + 2] = w1;
        xw[0][4 * t + 3] = w2;
        xw[0][4 * t + 4] = w3;

        if (t < 64) {                  // tile0 lo halo (l = lbase0-1)
            int l = lbase0 - 1;
            float v = (l >= 0) ? xrow[(size_t)t * LLEN + l] : 0.0f;
            u64 word = __ballot(v >= alpha[t]);
            if (t == 0) xw[0][0] = word;           // garbage if l<0; EDGE=1 fixes
        } else if (t < 128) {          // tile0 hi halo (l = lbase0+LTILE < LLEN)
            int ci = t - 64;
            float v = xrow[(size_t)ci * LLEN + (lbase0 + LTILE)];
            u64 word = __ballot(v >= alpha[ci]);
            if (ci == 0) xw[0][LTILE + 1] = word;
        }
    }
    __syncthreads();

    // tile0 window
    const u64 a0 = xw[0][4 * t + 0], a1 = xw[0][4 * t + 1],
              a2 = xw[0][4 * t + 2], a3 = xw[0][4 * t + 3],
              a4 = xw[0][4 * t + 4], a5 = xw[0][4 * t + 5];
    float* outp0 = out + (size_t)b * COUT * LLEN + lbase0 + 4 * t;
    float* outp1 = outp0 + LTILE;

    // ---- iteration 0: compute tile0 || prefetch+pack tile1 ----
    const float* xb1 = xrow + lbase1 + 4 * t;
    u64 n0 = 0, n1 = 0, n2 = 0, n3 = 0;
    if (blockIdx.x == 0)
        iter0<1>(rec, xb1, alpha, a0, a1, a2, a3, a4, a5, t == 0, outp0,
                 n0, n1, n2, n3);
    else
        iter0<0>(rec, xb1, alpha, a0, a1, a2, a3, a4, a5, false, outp0,
                 n0, n1, n2, n3);

    xw[1][4 * t + 1] = n0;
    xw[1][4 * t + 2] = n1;
    xw[1][4 * t + 3] = n2;
    xw[1][4 * t + 4] = n3;
    if (t == 0) xw[1][0] = xw[0][LTILE];   // tile1 lo halo = tile0 last word
    if (t >= 64 && t < 128) {              // tile1 hi halo (l = lbase1+LTILE)
        int ci = t - 64;
        int l = lbase1 + LTILE;
        float v = (l < LLEN) ? xrow[(size_t)ci * LLEN + l] : 0.0f;
        u64 word = __ballot(v >= alpha[ci]);
        if (ci == 0) xw[1][LTILE + 1] = word;  // garbage if l>=LLEN; EDGE=2 fixes
    }
    __syncthreads();

    // ---- iteration 1: compute tile1 (no prefetch) ----
    const u64 c0 = xw[1][4 * t + 0], c1 = xw[1][4 * t + 1],
              c2 = xw[1][4 * t + 2], c3 = xw[1][4 * t + 3],
              c4 = xw[1][4 * t + 4], c5 = xw[1][4 * t + 5];
    if (blockIdx.x == gridDim.x - 1)
        co_range<2>(rec, 0, COUT, c0, c1, c2, c3, c4, c5, t == 255, outp1);
    else
        co_range<0>(rec, 0, COUT, c0, c1, c2, c3, c4, c5, false, outp1);
}

extern "C" void kernel_launch(void* const* d_in, const int* in_sizes, int n_in,
                              void* d_out, int out_size, void* d_ws, size_t ws_size,
                              hipStream_t stream) {
    const float* x      = (const float*)d_in[0];
    const float* alpha  = (const float*)d_in[1];
    const float* w      = (const float*)d_in[2];
    const float* wscale = (const float*)d_in[3];
    const float* bias   = (const float*)d_in[4];
    const float* beta   = (const float*)d_in[5];
    const float* gamma  = (const float*)d_in[6];
    const float* zeta   = (const float*)d_in[7];
    float* out = (float*)d_out;

    WRec* rec = (WRec*)d_ws;   // 64 * 64 B = 4 KB

    pack_weights<<<1, 64, 0, stream>>>(w, wscale, bias, beta, gamma, zeta, rec);

    dim3 grid(LLEN / (LTILE * TPB), 16);
    bconv_kernel<<<grid, 256, 0, stream>>>(x, alpha, rec, out);
}